// Round 2
// baseline (165.936 us; speedup 1.0000x reference)
//
#include <hip/hip_runtime.h>

// Per-clause softmax-attention pooling.
// B=64, T=512, D=768, C=31 -> 32 segments per batch; segments partition [0,T).
// Segment lengths L in [2, 30] by construction (16 +/- jitter), so one block
// per (batch, segment); 2048 blocks total, 8 blocks/CU.

#define B_ 64
#define T_ 512
#define D_ 768
#define C_ 31
#define NSEG 32  // C+1

// block = 192 threads (3 waves). 192 * 4 = 768 = D, one float4 per thread.
__global__ __launch_bounds__(192) void seg_softmax_pool(
    const float* __restrict__ hidden,    // [B, T, D]
    const int*   __restrict__ clause_b,  // [B, C]
    const float* __restrict__ w5,        // [D] (D x 1)
    const float* __restrict__ b5,        // [1]
    float*       __restrict__ out)       // [B, NSEG, D]
{
    const int blk  = blockIdx.x;
    const int b    = blk >> 5;      // / NSEG
    const int j    = blk & 31;      // % NSEG
    const int tid  = threadIdx.x;
    const int wave = tid >> 6;
    const int lane = tid & 63;

    const int start = (j == 0)  ? 0  : clause_b[b * C_ + j - 1];
    const int end   = (j == C_) ? T_ : clause_b[b * C_ + j];
    const int L     = end - start;   // [2, 30] by construction (<= T_ worst case)

    __shared__ float s_scores[T_];   // raw scores
    __shared__ float s_w[T_];        // exp(s - m), later read as weights

    const float* hseg = hidden + ((size_t)b * T_ + start) * D_;

    // ---------------- Phase 1: scores[t] = <h[t,:], w5> + b5 ----------------
    // Wave (t % 3) owns token t. Lane covers d = {4*lane, 4*lane+256, 4*lane+512}.
    const float4 wv0 = *(const float4*)(w5 + 4 * lane);
    const float4 wv1 = *(const float4*)(w5 + 4 * lane + 256);
    const float4 wv2 = *(const float4*)(w5 + 4 * lane + 512);
    const float  bias = b5[0];

    for (int t = wave; t < L; t += 3) {
        const float* hp = hseg + (size_t)t * D_;
        const float4 h0 = *(const float4*)(hp + 4 * lane);
        const float4 h1 = *(const float4*)(hp + 4 * lane + 256);
        const float4 h2 = *(const float4*)(hp + 4 * lane + 512);
        float p = h0.x * wv0.x + h0.y * wv0.y + h0.z * wv0.z + h0.w * wv0.w
                + h1.x * wv1.x + h1.y * wv1.y + h1.z * wv1.z + h1.w * wv1.w
                + h2.x * wv2.x + h2.y * wv2.y + h2.z * wv2.z + h2.w * wv2.w;
        #pragma unroll
        for (int off = 32; off > 0; off >>= 1)
            p += __shfl_xor(p, off, 64);
        if (lane == 0) s_scores[t] = p + bias;
    }
    __syncthreads();

    // ---------------- Phase 1.5: softmax weights (one exp per token total) --
    // Max via broadcast LDS reads (cheap, L <= 30), then threads t < L each
    // compute ONE exp; denominator via broadcast scan of s_w.
    float m = -INFINITY;
    for (int t = 0; t < L; ++t) m = fmaxf(m, s_scores[t]);
    if (tid < L) s_w[tid] = __expf(s_scores[tid] - m);
    __syncthreads();

    float denom = 0.0f;
    for (int t = 0; t < L; ++t) denom += s_w[t];
    const float inv = 1.0f / denom;

    // ---------------- Phase 2: weighted pooling (no transcendentals) --------
    // Thread tid owns output elements d = 4*tid .. 4*tid+3. Rows come from L2
    // (phase 1 just fetched them).
    float4 acc = make_float4(0.f, 0.f, 0.f, 0.f);
    const float* hp = hseg + 4 * tid;
    for (int t = 0; t < L; ++t) {
        const float  w = s_w[t];                       // LDS broadcast
        const float4 h = *(const float4*)(hp + (size_t)t * D_);
        acc.x = fmaf(w, h.x, acc.x);
        acc.y = fmaf(w, h.y, acc.y);
        acc.z = fmaf(w, h.z, acc.z);
        acc.w = fmaf(w, h.w, acc.w);
    }
    acc.x *= inv; acc.y *= inv; acc.z *= inv; acc.w *= inv;

    float4* op = (float4*)(out + ((size_t)b * NSEG + j) * D_ + 4 * tid);
    *op = acc;
}

extern "C" void kernel_launch(void* const* d_in, const int* in_sizes, int n_in,
                              void* d_out, int out_size, void* d_ws, size_t ws_size,
                              hipStream_t stream) {
    const float* hidden   = (const float*)d_in[0];
    const int*   clause_b = (const int*)d_in[1];
    const float* w5       = (const float*)d_in[2];
    const float* b5       = (const float*)d_in[3];
    float*       out      = (float*)d_out;

    const int nblocks = B_ * NSEG;  // 2048
    seg_softmax_pool<<<nblocks, 192, 0, stream>>>(hidden, clause_b, w5, b5, out);
}

// Round 3
// 161.258 us; speedup vs baseline: 1.0290x; 1.0290x over previous
//
#include <hip/hip_runtime.h>

// Per-clause softmax-attention pooling — single-pass online-softmax version.
// B=64, T=512, D=768, C=31 -> 32 segments/batch, 2048 segments total.
// ONE WAVE per segment: D=768 -> 12 floats/lane (3 float4 chunks). Score
// reduction is a pure wave shfl (no barriers -> no vmcnt(0) drains), so each
// hidden row is read from HBM exactly once while it lives in registers:
//   s_t   = <h_t, w5> + b5          (wave shfl-reduce)
//   m'    = max(m, s_t); scale = exp(m-m'); e = exp(s_t-m')
//   acc   = acc*scale + e*h_t;  denom = denom*scale + e
// Minimal HBM traffic: 100.7 MB read + 6.3 MB write (~17 us floor).

#define B_ 64
#define T_ 512
#define D_ 768
#define C_ 31
#define NSEG 32  // C+1

__global__ __launch_bounds__(256) void seg_softmax_pool_online(
    const float* __restrict__ hidden,    // [B, T, D]
    const int*   __restrict__ clause_b,  // [B, C]
    const float* __restrict__ w5,        // [D]
    const float* __restrict__ b5,        // [1]
    float*       __restrict__ out)       // [B, NSEG, D]
{
    const int wave = threadIdx.x >> 6;
    const int lane = threadIdx.x & 63;
    const int seg  = blockIdx.x * 4 + wave;   // 0..2047
    const int b    = seg >> 5;                // / NSEG
    const int j    = seg & 31;                // % NSEG

    const int start = (j == 0)  ? 0  : clause_b[b * C_ + j - 1];
    const int end   = (j == C_) ? T_ : clause_b[b * C_ + j];
    const int L     = end - start;            // [2, 30] by construction

    // Lane owns dims d = c*256 + 4*lane + {0..3}, c in {0,1,2}.
    const int doff = 4 * lane;
    const float4 w0 = *(const float4*)(w5 + doff);
    const float4 w1 = *(const float4*)(w5 + doff + 256);
    const float4 w2 = *(const float4*)(w5 + doff + 512);
    const float bias = b5[0];

    const float* hseg = hidden + ((size_t)b * T_ + start) * D_ + doff;

    float4 a0 = make_float4(0.f, 0.f, 0.f, 0.f);
    float4 a1 = a0, a2 = a0;
    float m = -INFINITY, denom = 0.0f;

    // Prefetch row 0.
    float4 c0 = *(const float4*)(hseg);
    float4 c1 = *(const float4*)(hseg + 256);
    float4 c2 = *(const float4*)(hseg + 512);

    for (int t = 0; t < L; ++t) {
        // Prefetch row t+1 while we reduce row t (no barrier in between;
        // shfl is LDS-pipe (lgkmcnt), loads stay outstanding on vmcnt).
        float4 n0 = make_float4(0.f, 0.f, 0.f, 0.f), n1 = n0, n2 = n0;
        if (t + 1 < L) {
            const float* np = hseg + (size_t)(t + 1) * D_;
            n0 = *(const float4*)(np);
            n1 = *(const float4*)(np + 256);
            n2 = *(const float4*)(np + 512);
        }

        // Partial dot product, then 6-step wave-64 butterfly reduce.
        float p = c0.x * w0.x + c0.y * w0.y + c0.z * w0.z + c0.w * w0.w
                + c1.x * w1.x + c1.y * w1.y + c1.z * w1.z + c1.w * w1.w
                + c2.x * w2.x + c2.y * w2.y + c2.z * w2.z + c2.w * w2.w;
        #pragma unroll
        for (int off = 32; off > 0; off >>= 1)
            p += __shfl_xor(p, off, 64);
        const float s = p + bias;

        // Online softmax update.
        const float mn    = fmaxf(m, s);
        const float scale = __expf(m - mn);   // 0 on first iter (m=-inf)
        const float e     = __expf(s - mn);
        denom = denom * scale + e;
        a0.x = a0.x * scale + e * c0.x;  a0.y = a0.y * scale + e * c0.y;
        a0.z = a0.z * scale + e * c0.z;  a0.w = a0.w * scale + e * c0.w;
        a1.x = a1.x * scale + e * c1.x;  a1.y = a1.y * scale + e * c1.y;
        a1.z = a1.z * scale + e * c1.z;  a1.w = a1.w * scale + e * c1.w;
        a2.x = a2.x * scale + e * c2.x;  a2.y = a2.y * scale + e * c2.y;
        a2.z = a2.z * scale + e * c2.z;  a2.w = a2.w * scale + e * c2.w;
        m = mn;
        c0 = n0; c1 = n1; c2 = n2;
    }

    const float inv = 1.0f / denom;
    float* op = out + ((size_t)b * NSEG + j) * D_ + doff;
    *(float4*)(op)       = make_float4(a0.x * inv, a0.y * inv, a0.z * inv, a0.w * inv);
    *(float4*)(op + 256) = make_float4(a1.x * inv, a1.y * inv, a1.z * inv, a1.w * inv);
    *(float4*)(op + 512) = make_float4(a2.x * inv, a2.y * inv, a2.z * inv, a2.w * inv);
}

extern "C" void kernel_launch(void* const* d_in, const int* in_sizes, int n_in,
                              void* d_out, int out_size, void* d_ws, size_t ws_size,
                              hipStream_t stream) {
    const float* hidden   = (const float*)d_in[0];
    const int*   clause_b = (const int*)d_in[1];
    const float* w5       = (const float*)d_in[2];
    const float* b5       = (const float*)d_in[3];
    float*       out      = (float*)d_out;

    // 2048 segments, 4 waves (segments) per 256-thread block -> 512 blocks.
    seg_softmax_pool_online<<<B_ * NSEG / 4, 256, 0, stream>>>(hidden, clause_b, w5, b5, out);
}

// Round 4
// 155.592 us; speedup vs baseline: 1.0665x; 1.0364x over previous
//
#include <hip/hip_runtime.h>

// Per-clause softmax-attention pooling — flash-style token-split version.
// B=64, T=512, D=768, C=31 -> 32 segments/batch, 2048 segments total.
//
// One 256-thread block (4 waves) per segment. Wave w handles tokens
// t = w, w+4, ... with a PRIVATE online softmax (m, denom, acc[12]); each
// hidden row is read from HBM exactly once, score reduce is an in-wave
// 6-step shfl butterfly (no barriers in the token loop). At the end the 4
// waves merge via LDS (flash-attention style rescale):
//   M = max_w m_w;  T = sum_w d_w*exp(m_w-M);  out = sum_w exp(m_w-M)*acc_w / T
// 8192 waves (8/SIMD) vs round-3's 2048 (2/SIMD) -> load latency hidden.

#define B_ 64
#define T_ 512
#define D_ 768
#define C_ 31
#define NSEG 32  // C+1

__global__ __launch_bounds__(256) void seg_softmax_pool_split(
    const float* __restrict__ hidden,    // [B, T, D]
    const int*   __restrict__ clause_b,  // [B, C]
    const float* __restrict__ w5,        // [D]
    const float* __restrict__ b5,        // [1]
    float*       __restrict__ out)       // [B, NSEG, D]
{
    const int tid  = threadIdx.x;
    const int wave = tid >> 6;
    const int lane = tid & 63;
    const int seg  = blockIdx.x;              // 0..2047
    const int b    = seg >> 5;                // / NSEG
    const int j    = seg & 31;                // % NSEG

    const int start = (j == 0)  ? 0  : clause_b[b * C_ + j - 1];
    const int end   = (j == C_) ? T_ : clause_b[b * C_ + j];
    const int L     = end - start;            // [2, 30] by construction

    // Lane owns dims d = c*256 + 4*lane + {0..3}, c in {0,1,2}.
    const int doff = 4 * lane;
    const float4 w0 = *(const float4*)(w5 + doff);
    const float4 w1 = *(const float4*)(w5 + doff + 256);
    const float4 w2 = *(const float4*)(w5 + doff + 512);
    const float bias = b5[0];

    const float* hseg = hidden + ((size_t)b * T_ + start) * D_ + doff;

    float4 a0 = make_float4(0.f, 0.f, 0.f, 0.f);
    float4 a1 = a0, a2 = a0;
    float m = -INFINITY, denom = 0.0f;

    // Prefetch this wave's first row (guarded: don't run past the buffer).
    float4 c0 = a0, c1 = a0, c2 = a0;
    if (wave < L) {
        const float* p0 = hseg + (size_t)wave * D_;
        c0 = *(const float4*)(p0);
        c1 = *(const float4*)(p0 + 256);
        c2 = *(const float4*)(p0 + 512);
    }

    for (int t = wave; t < L; t += 4) {
        // Prefetch row t+4 while reducing row t (no barrier in the loop).
        float4 n0 = make_float4(0.f, 0.f, 0.f, 0.f), n1 = n0, n2 = n0;
        if (t + 4 < L) {
            const float* np = hseg + (size_t)(t + 4) * D_;
            n0 = *(const float4*)(np);
            n1 = *(const float4*)(np + 256);
            n2 = *(const float4*)(np + 512);
        }

        float p = c0.x * w0.x + c0.y * w0.y + c0.z * w0.z + c0.w * w0.w
                + c1.x * w1.x + c1.y * w1.y + c1.z * w1.z + c1.w * w1.w
                + c2.x * w2.x + c2.y * w2.y + c2.z * w2.z + c2.w * w2.w;
        #pragma unroll
        for (int off = 32; off > 0; off >>= 1)
            p += __shfl_xor(p, off, 64);
        const float s = p + bias;

        const float mn    = fmaxf(m, s);
        const float scale = __expf(m - mn);   // 0 on first token (m = -inf)
        const float e     = __expf(s - mn);
        denom = denom * scale + e;
        a0.x = a0.x * scale + e * c0.x;  a0.y = a0.y * scale + e * c0.y;
        a0.z = a0.z * scale + e * c0.z;  a0.w = a0.w * scale + e * c0.w;
        a1.x = a1.x * scale + e * c1.x;  a1.y = a1.y * scale + e * c1.y;
        a1.z = a1.z * scale + e * c1.z;  a1.w = a1.w * scale + e * c1.w;
        a2.x = a2.x * scale + e * c2.x;  a2.y = a2.y * scale + e * c2.y;
        a2.z = a2.z * scale + e * c2.z;  a2.w = a2.w * scale + e * c2.w;
        m = mn;
        c0 = n0; c1 = n1; c2 = n2;
    }

    // ---- Cross-wave merge (flash-attention rescale) ----
    __shared__ float s_acc[4][D_];   // 12 KB
    __shared__ float s_m[4], s_d[4];

    if (lane == 0) { s_m[wave] = m; s_d[wave] = denom; }
    __syncthreads();

    const float M = fmaxf(fmaxf(s_m[0], s_m[1]), fmaxf(s_m[2], s_m[3]));
    const float Tden = s_d[0] * __expf(s_m[0] - M) + s_d[1] * __expf(s_m[1] - M)
                     + s_d[2] * __expf(s_m[2] - M) + s_d[3] * __expf(s_m[3] - M);
    const float myscale = __expf(m - M);      // 0 for token-less waves (m=-inf)

    float* dst = &s_acc[wave][doff];
    *(float4*)(dst)       = make_float4(a0.x * myscale, a0.y * myscale, a0.z * myscale, a0.w * myscale);
    *(float4*)(dst + 256) = make_float4(a1.x * myscale, a1.y * myscale, a1.z * myscale, a1.w * myscale);
    *(float4*)(dst + 512) = make_float4(a2.x * myscale, a2.y * myscale, a2.z * myscale, a2.w * myscale);
    __syncthreads();

    // Each thread owns dims d = tid, tid+256, tid+512.
    const float inv = 1.0f / Tden;
    float* op = out + ((size_t)b * NSEG + j) * D_;
    #pragma unroll
    for (int k = 0; k < 3; ++k) {
        const int d = tid + k * 256;
        const float v = s_acc[0][d] + s_acc[1][d] + s_acc[2][d] + s_acc[3][d];
        op[d] = v * inv;
    }
}

extern "C" void kernel_launch(void* const* d_in, const int* in_sizes, int n_in,
                              void* d_out, int out_size, void* d_ws, size_t ws_size,
                              hipStream_t stream) {
    const float* hidden   = (const float*)d_in[0];
    const int*   clause_b = (const int*)d_in[1];
    const float* w5       = (const float*)d_in[2];
    const float* b5       = (const float*)d_in[3];
    float*       out      = (float*)d_out;

    // One block per segment: 2048 blocks x 256 threads = 8192 waves.
    seg_softmax_pool_split<<<B_ * NSEG, 256, 0, stream>>>(hidden, clause_b, w5, b5, out);
}